// Round 9
// baseline (118.269 us; speedup 1.0000x reference)
//
#include <hip/hip_runtime.h>
#include <hip/hip_fp16.h>

// B=4, S=512, D=256, UNITS=128. out: [B,S,D] fp32.
#define SEQ 512
#define DIM 256
#define UN  128
#define BSZ 2048                       // B*S
#define CSC 2.8853900817779268f        // 2*log2(e)

struct h4v { __half2 a, b; };          // 8B = 4 f16

static __device__ __forceinline__ unsigned short f2bf(float x) {  // RNE, x>0 finite
  unsigned u = __float_as_uint(x);
  u += 0x7FFF + ((u >> 16) & 1);
  return (unsigned short)(u >> 16);
}
static __device__ __forceinline__ float bf2f(unsigned short s) {
  return __uint_as_float((unsigned)s << 16);
}
static __device__ __forceinline__ float rdlane(float v, int k) {
  return __int_as_float(__builtin_amdgcn_readlane(__float_as_int(v), k));
}

// ---- proj: Eq = exp2(CSC*(values@Wq)) [BSZ][UN] fp32,
//            Ev = bf16(exp2(CSC*(values@Wv)))^T [UN][BSZ],
//            Vf16 = f16(values) [BSZ][DIM]
__global__ __launch_bounds__(256) void proj_kernel(
    const float* __restrict__ values, const float* __restrict__ Wq,
    const float* __restrict__ Wv, float* __restrict__ Eq,
    unsigned short* __restrict__ Ev, __half* __restrict__ Vf16) {
  __shared__ float vsm[4 * DIM];
  const int t = threadIdx.x;
  const int r0 = blockIdx.x * 4;
  {
    const int row = t >> 6, c4 = (t & 63) * 4;
    const float4 v = *(const float4*)(values + (r0 + row) * DIM + c4);
    *(float4*)&vsm[row * DIM + c4] = v;
    __half2* vf = (__half2*)(Vf16 + (r0 + row) * DIM + c4);
    vf[0] = __floats2half2_rn(v.x, v.y);
    vf[1] = __floats2half2_rn(v.z, v.w);
  }
  __syncthreads();
  const int half = t >> 7, u = t & 127;
  const float* __restrict__ W = half ? Wv : Wq;
  float acc[4] = {0.f, 0.f, 0.f, 0.f};
  for (int d = 0; d < DIM; d += 4) {
    const float w0 = W[(d + 0) * UN + u], w1 = W[(d + 1) * UN + u];
    const float w2 = W[(d + 2) * UN + u], w3 = W[(d + 3) * UN + u];
#pragma unroll
    for (int k = 0; k < 4; ++k) {
      const float4 v = *(const float4*)&vsm[k * DIM + d];
      acc[k] = fmaf(v.x, w0, acc[k]);
      acc[k] = fmaf(v.y, w1, acc[k]);
      acc[k] = fmaf(v.z, w2, acc[k]);
      acc[k] = fmaf(v.w, w3, acc[k]);
    }
  }
  if (!half) {
#pragma unroll
    for (int k = 0; k < 4; ++k)
      Eq[(r0 + k) * UN + u] = __builtin_amdgcn_exp2f(acc[k] * CSC);
  } else {
    ushort4 o;
    o.x = f2bf(__builtin_amdgcn_exp2f(acc[0] * CSC));
    o.y = f2bf(__builtin_amdgcn_exp2f(acc[1] * CSC));
    o.z = f2bf(__builtin_amdgcn_exp2f(acc[2] * CSC));
    o.w = f2bf(__builtin_amdgcn_exp2f(acc[3] * CSC));
    *(ushort4*)(Ev + (size_t)u * BSZ + r0) = o;   // 8B aligned
  }
}

// ---- score: block = (b, pair p) rows {p, 511-p}. Every wave does EXACTLY
// 32 dual-row iters + 32 single-row iters (u-quarter per wave) -> zero SIMD skew.
// Writes normalized probs P (f16) to ws; zeros for masked lo slots. Then exits.
__global__ __launch_bounds__(256, 4) void score_kernel(
    const float* __restrict__ Eq, const unsigned short* __restrict__ Ev,
    const float* __restrict__ Vw, __half* __restrict__ P) {
  __shared__ float slo[4 * 256];   // [u-quarter][j<256] lo-row sdot partials
  __shared__ float shi[4 * SEQ];   // [u-quarter][j]      hi-row sdot partials
  __shared__ float red[16];

  const int t = threadIdx.x;
  const int l = t & 63, w = t >> 6;
  const int b = blockIdx.x >> 8, p = blockIdx.x & 255;
  const int bS = b * SEQ;
  const int i = p;                  // low row, i <= 255
  const int ihi = SEQ - 1 - p;      // high row, jhi >= 256
  const int jhi = ihi;

  const float* __restrict__ eql = Eq + (size_t)(bS + i) * UN;
  const float* __restrict__ eqh = Eq + (size_t)(bS + ihi) * UN;
  const int uq = w << 5;            // this wave's u-quarter [uq, uq+32)

  // preload 32 loop-uniforms into lanes 0..31 (dup in 32..63)
  const int lk = l & 31;
  const float qlv = eql[uq + lk];
  const float qhv = eqh[uq + lk];
  const float wv  = Vw[uq + lk];

#define LDE(PTR, K) (*(const ushort4*)((PTR) + (size_t)(K) * BSZ))
  // ---- part 1: dual rows, j = 4l..4l+3 (< 256), 32 u-iters ----
  {
    const unsigned short* __restrict__ evp = Ev + (size_t)uq * BSZ + bS + (l << 2);
    float h0=0.f,h1=0.f,h2=0.f,h3=0.f,l0=0.f,l1=0.f,l2=0.f,l3=0.f;
    ushort4 e0 = LDE(evp,0), e1 = LDE(evp,1), e2 = LDE(evp,2), e3 = LDE(evp,3);
#define PRD(EC, KK) { \
    const float qh = rdlane(qhv, (KK)); \
    const float ql = rdlane(qlv, (KK)); \
    const float ww = rdlane(wv,  (KK)); \
    const float f0 = bf2f(EC.x), f1 = bf2f(EC.y), f2 = bf2f(EC.z), f3 = bf2f(EC.w); \
    h0 = fmaf(ww, __builtin_amdgcn_rcpf(fmaf(qh, f0, 1.f)), h0); \
    h1 = fmaf(ww, __builtin_amdgcn_rcpf(fmaf(qh, f1, 1.f)), h1); \
    h2 = fmaf(ww, __builtin_amdgcn_rcpf(fmaf(qh, f2, 1.f)), h2); \
    h3 = fmaf(ww, __builtin_amdgcn_rcpf(fmaf(qh, f3, 1.f)), h3); \
    l0 = fmaf(ww, __builtin_amdgcn_rcpf(fmaf(ql, f0, 1.f)), l0); \
    l1 = fmaf(ww, __builtin_amdgcn_rcpf(fmaf(ql, f1, 1.f)), l1); \
    l2 = fmaf(ww, __builtin_amdgcn_rcpf(fmaf(ql, f2, 1.f)), l2); \
    l3 = fmaf(ww, __builtin_amdgcn_rcpf(fmaf(ql, f3, 1.f)), l3); }
    for (int k = 0; k < 32; k += 4) {
      // prefetch overshoot (u-offset <= 35 -> Ev row <= 131) lands in Vf16: valid mem
      ushort4 n;
      n = LDE(evp, k + 4); PRD(e0, k + 0); e0 = n;
      n = LDE(evp, k + 5); PRD(e1, k + 1); e1 = n;
      n = LDE(evp, k + 6); PRD(e2, k + 2); e2 = n;
      n = LDE(evp, k + 7); PRD(e3, k + 3); e3 = n;
    }
#undef PRD
    *(float4*)&slo[(w << 8) + (l << 2)] = make_float4(l0, l1, l2, l3);
    *(float4*)&shi[(w << 9) + (l << 2)] = make_float4(h0, h1, h2, h3);
  }
  // ---- part 2: hi row only, j = 256+4l (if <= jhi), 32 u-iters ----
  if (256 + (l << 2) <= jhi) {
    const unsigned short* __restrict__ evp = Ev + (size_t)uq * BSZ + bS + 256 + (l << 2);
    float h0=0.f,h1=0.f,h2=0.f,h3=0.f;
    ushort4 e0 = LDE(evp,0), e1 = LDE(evp,1), e2 = LDE(evp,2), e3 = LDE(evp,3);
#define PRS(EC, KK) { \
    const float qh = rdlane(qhv, (KK)); \
    const float ww = rdlane(wv,  (KK)); \
    h0 = fmaf(ww, __builtin_amdgcn_rcpf(fmaf(qh, bf2f(EC.x), 1.f)), h0); \
    h1 = fmaf(ww, __builtin_amdgcn_rcpf(fmaf(qh, bf2f(EC.y), 1.f)), h1); \
    h2 = fmaf(ww, __builtin_amdgcn_rcpf(fmaf(qh, bf2f(EC.z), 1.f)), h2); \
    h3 = fmaf(ww, __builtin_amdgcn_rcpf(fmaf(qh, bf2f(EC.w), 1.f)), h3); }
    for (int k = 0; k < 32; k += 4) {
      ushort4 n;
      n = LDE(evp, k + 4); PRS(e0, k + 0); e0 = n;
      n = LDE(evp, k + 5); PRS(e1, k + 1); e1 = n;
      n = LDE(evp, k + 6); PRS(e2, k + 2); e2 = n;
      n = LDE(evp, k + 7); PRS(e3, k + 3); e3 = n;
    }
#undef PRS
    *(float4*)&shi[(w << 9) + 256 + (l << 2)] = make_float4(h0, h1, h2, h3);
  }
#undef LDE
  __syncthreads();

  // ---- softmax (all 256 threads, both rows at once) ----
  const float sLo = slo[t] + slo[256 + t] + slo[512 + t] + slo[768 + t];
  const float sHa = shi[t] + shi[512 + t] + shi[1024 + t] + shi[1536 + t];
  const int t2 = 256 + t;
  const float sHb = shi[t2] + shi[512 + t2] + shi[1024 + t2] + shi[1536 + t2];
  const bool vLo = (t <= i);
  const bool vHb = (t2 <= jhi);

  float mLo = vLo ? sLo : 1e30f;                 // min sdot == max score
  float mHi = fminf(sHa, vHb ? sHb : 1e30f);
#pragma unroll
  for (int o = 32; o; o >>= 1) {
    mLo = fminf(mLo, __shfl_xor(mLo, o));
    mHi = fminf(mHi, __shfl_xor(mHi, o));
  }
  if (l == 0) { red[w] = mLo; red[4 + w] = mHi; }
  __syncthreads();
  mLo = fminf(fminf(red[0], red[1]), fminf(red[2], red[3]));
  mHi = fminf(fminf(red[4], red[5]), fminf(red[6], red[7]));

  const float pLo = vLo ? __builtin_amdgcn_exp2f((mLo - sLo) * CSC) : 0.f;
  const float pHa = __builtin_amdgcn_exp2f((mHi - sHa) * CSC);
  const float pHb = vHb ? __builtin_amdgcn_exp2f((mHi - sHb) * CSC) : 0.f;
  float suLo = pLo, suHi = pHa + pHb;
#pragma unroll
  for (int o = 32; o; o >>= 1) {
    suLo += __shfl_xor(suLo, o);
    suHi += __shfl_xor(suHi, o);
  }
  if (l == 0) { red[8 + w] = suLo; red[12 + w] = suHi; }
  __syncthreads();
  const float invLo = __builtin_amdgcn_rcpf(red[8] + red[9] + red[10] + red[11]);
  const float invHi = __builtin_amdgcn_rcpf(red[12] + red[13] + red[14] + red[15]);

  P[(size_t)(bS + i) * SEQ + t]   = __float2half(pLo * invLo);  // zeros for t>i
  P[(size_t)(bS + ihi) * SEQ + t] = __float2half(pHa * invHi);
  if (vHb) P[(size_t)(bS + ihi) * SEQ + t2] = __float2half(pHb * invHi);
}

// ---- ctx: out = P @ values (normalization already folded into P) ----
__global__ __launch_bounds__(256, 4) void ctx_kernel(
    const __half* __restrict__ Vf16, const __half* __restrict__ P,
    float* __restrict__ out) {
  __shared__ float part[8 * DIM];   // [wave g][2 rows][DIM]
  const int t = threadIdx.x, lane = t & 63, g = t >> 6;
  const int b = blockIdx.x >> 8, p = blockIdx.x & 255;
  const int bS = b * SEQ;
  const int i = p, ihi = SEQ - 1 - p, jhi = ihi;

  const __half* __restrict__ Plo = P + (size_t)(bS + i) * SEQ;
  const __half* __restrict__ Phi = P + (size_t)(bS + ihi) * SEQ;
  const int d4 = lane << 2;

  // preload probs to lane registers: lane k holds j = g+4k (loop1), 256+g+4k (loop2)
  const float plo0 = __half2float(Plo[g + (lane << 2)]);
  const float phi0 = __half2float(Phi[g + (lane << 2)]);
  const int j1 = 256 + g + (lane << 2);
  const float phi1 = (j1 <= jhi) ? __half2float(Phi[j1]) : 0.f;

  float a0=0.f,a1=0.f,a2=0.f,a3=0.f, c0=0.f,c1=0.f,c2=0.f,c3=0.f;
  const __half* __restrict__ vb = Vf16 + (size_t)bS * DIM + d4;
  h4v vc = *(const h4v*)(vb + g * DIM);
  // loop 1: j = g+4k < 256 <= jhi: dual row, branch-free (lo probs zeroed by score)
#pragma unroll 8
  for (int k = 0; k < 64; ++k) {
    const h4v vn = *(const h4v*)(vb + (size_t)(g + 4 * k + 4) * DIM);  // row<=bS+259: valid
    const float pl = rdlane(plo0, k), ph = rdlane(phi0, k);
    const float2 f01 = __half22float2(vc.a), f23 = __half22float2(vc.b);
    a0 = fmaf(pl, f01.x, a0); a1 = fmaf(pl, f01.y, a1);
    a2 = fmaf(pl, f23.x, a2); a3 = fmaf(pl, f23.y, a3);
    c0 = fmaf(ph, f01.x, c0); c1 = fmaf(ph, f01.y, c1);
    c2 = fmaf(ph, f23.x, c2); c3 = fmaf(ph, f23.y, c3);
    vc = vn;
  }
  // loop 2: j = g+256 .. jhi: high row only
  int k2 = 0;
#pragma unroll 4
  for (int j = g + 256; j <= jhi; j += 4, ++k2) {
    const int jn = (j + 4 <= jhi) ? j + 4 : jhi;
    const h4v vn = *(const h4v*)(vb + (size_t)jn * DIM);
    const float ph = rdlane(phi1, k2);
    const float2 f01 = __half22float2(vc.a), f23 = __half22float2(vc.b);
    c0 = fmaf(ph, f01.x, c0); c1 = fmaf(ph, f01.y, c1);
    c2 = fmaf(ph, f23.x, c2); c3 = fmaf(ph, f23.y, c3);
    vc = vn;
  }
  *(float4*)&part[(g * 2 + 0) * DIM + d4] = make_float4(a0, a1, a2, a3);
  *(float4*)&part[(g * 2 + 1) * DIM + d4] = make_float4(c0, c1, c2, c3);
  __syncthreads();

  const float olo = part[t] + part[2 * DIM + t] + part[4 * DIM + t] + part[6 * DIM + t];
  const float ohi = part[DIM + t] + part[3 * DIM + t] + part[5 * DIM + t] + part[7 * DIM + t];
  out[(size_t)(bS + i) * DIM + t] = olo;
  out[(size_t)(bS + ihi) * DIM + t] = ohi;
}

extern "C" void kernel_launch(void* const* d_in, const int* in_sizes, int n_in,
                              void* d_out, int out_size, void* d_ws, size_t ws_size,
                              hipStream_t stream) {
  const float* values = (const float*)d_in[0];
  const float* Wq     = (const float*)d_in[1];
  const float* Wv     = (const float*)d_in[2];
  const float* Vw     = (const float*)d_in[3];
  float* out = (float*)d_out;
  float* Eq = (float*)d_ws;                                       // 1 MB
  unsigned short* Ev = (unsigned short*)(Eq + (size_t)BSZ * UN);  // 512 KB
  __half* Vf16 = (__half*)(Ev + (size_t)UN * BSZ);                // 1 MB (Ev-prefetch overshoot target)
  __half* P = Vf16 + (size_t)BSZ * DIM;                           // [BSZ][SEQ] f16, 2 MB
  proj_kernel<<<dim3(BSZ / 4), 256, 0, stream>>>(values, Wq, Wv, Eq, Ev, Vf16);
  score_kernel<<<dim3(4 * 256), 256, 0, stream>>>(Eq, Ev, Vw, P);
  ctx_kernel<<<dim3(4 * 256), 256, 0, stream>>>(Vf16, P, out);
}

// Round 10
// 98.179 us; speedup vs baseline: 1.2046x; 1.2046x over previous
//
#include <hip/hip_runtime.h>
#include <hip/hip_fp16.h>

// B=4, S=512, D=256, UNITS=128. out: [B,S,D] fp32.
#define SEQ 512
#define DIM 256
#define UN  128
#define BSZ 2048                       // B*S
#define CSC 2.8853900817779268f        // 2*log2(e)

typedef _Float16 half8 __attribute__((ext_vector_type(8)));
typedef float   float4v __attribute__((ext_vector_type(4)));
struct h4s { __half2 a, b; };          // 8B = 4 f16

static __device__ __forceinline__ unsigned short f2bf(float x) {  // RNE, x>0 finite
  unsigned u = __float_as_uint(x);
  u += 0x7FFF + ((u >> 16) & 1);
  return (unsigned short)(u >> 16);
}
static __device__ __forceinline__ float bf2f(unsigned short s) {
  return __uint_as_float((unsigned)s << 16);
}

// ---- proj: Eq = exp2(CSC*(values@Wq)) [BSZ][UN] fp32,
//            Ev = bf16(exp2(CSC*(values@Wv)))^T [UN][BSZ],
//            Vt = f16(values)^T [DIM][BSZ]  (B-operand layout for MFMA ctx)
__global__ __launch_bounds__(256) void proj_kernel(
    const float* __restrict__ values, const float* __restrict__ Wq,
    const float* __restrict__ Wv, float* __restrict__ Eq,
    unsigned short* __restrict__ Ev, _Float16* __restrict__ Vt) {
  __shared__ float vsm[4 * DIM];
  const int t = threadIdx.x;
  const int r0 = blockIdx.x * 4;
  {
    const int row = t >> 6, c4 = (t & 63) * 4;
    const float4 v = *(const float4*)(values + (r0 + row) * DIM + c4);
    *(float4*)&vsm[row * DIM + c4] = v;
  }
  __syncthreads();
  // transposed f16 write: thread t owns column d=t, 4 rows -> 8B store
  {
    h4s o;
    o.a = __floats2half2_rn(vsm[0 * DIM + t], vsm[1 * DIM + t]);
    o.b = __floats2half2_rn(vsm[2 * DIM + t], vsm[3 * DIM + t]);
    *(h4s*)(Vt + (size_t)t * BSZ + r0) = o;
  }
  const int half = t >> 7, u = t & 127;
  const float* __restrict__ W = half ? Wv : Wq;
  float acc[4] = {0.f, 0.f, 0.f, 0.f};
  for (int d = 0; d < DIM; d += 4) {
    const float w0 = W[(d + 0) * UN + u], w1 = W[(d + 1) * UN + u];
    const float w2 = W[(d + 2) * UN + u], w3 = W[(d + 3) * UN + u];
#pragma unroll
    for (int k = 0; k < 4; ++k) {
      const float4 v = *(const float4*)&vsm[k * DIM + d];
      acc[k] = fmaf(v.x, w0, acc[k]);
      acc[k] = fmaf(v.y, w1, acc[k]);
      acc[k] = fmaf(v.z, w2, acc[k]);
      acc[k] = fmaf(v.w, w3, acc[k]);
    }
  }
  if (!half) {
#pragma unroll
    for (int k = 0; k < 4; ++k)
      Eq[(r0 + k) * UN + u] = __builtin_amdgcn_exp2f(acc[k] * CSC);
  } else {
    ushort4 o;
    o.x = f2bf(__builtin_amdgcn_exp2f(acc[0] * CSC));
    o.y = f2bf(__builtin_amdgcn_exp2f(acc[1] * CSC));
    o.z = f2bf(__builtin_amdgcn_exp2f(acc[2] * CSC));
    o.w = f2bf(__builtin_amdgcn_exp2f(acc[3] * CSC));
    *(ushort4*)(Ev + (size_t)u * BSZ + r0) = o;   // 8B aligned
  }
}

// ---- score: block = (b, pair p), rows {p, 511-p} (r7 structure verbatim).
// Writes NORMALIZED probs P (f16, zeros in masked slots): lo row cols [0,256),
// hi row cols [0,512). Exits (no phase C).
__global__ __launch_bounds__(256, 4) void score_kernel(
    const float* __restrict__ Eq, const unsigned short* __restrict__ Ev,
    const float* __restrict__ Vw, _Float16* __restrict__ P) {
  __shared__ float sc[2 * SEQ];     // u-half-0 sdot -> probs. [lo | hi]
  __shared__ float scp[2 * SEQ];    // u-half-1 sdot partials
  __shared__ float invs[2];

  const int t = threadIdx.x;
  const int b = blockIdx.x >> 8, p = blockIdx.x & 255;
  const int bS = b * SEQ;
  const int i = p;                  // low row: j in [0, i], i <= 255
  const int ihi = SEQ - 1 - p;      // high row: j in [0, jhi], jhi >= 256
  const int jhi = ihi;

  const float* __restrict__ eql = Eq + (size_t)(bS + i) * UN;    // uniform -> s_load
  const float* __restrict__ eqh = Eq + (size_t)(bS + ihi) * UN;

  // ---- phase A (r7): thread owns j-quad (8B bf16 Ev load) x u-half; depth-4 prefetch
  {
    const int qd = t & 127, jb = qd << 2;
    const int u0 = (t >> 7) << 6;
    float* __restrict__ so = (t >> 7) ? scp : sc;
    const unsigned short* __restrict__ evp = Ev + (size_t)u0 * BSZ + bS + jb;
#define LDE(K) (*(const ushort4*)(evp + (size_t)(K) * BSZ))
    if ((t & 64) == 0) {            // waves 0,2: jb < 256 -> dual row
      float h0=0.f,h1=0.f,h2=0.f,h3=0.f,l0=0.f,l1=0.f,l2=0.f,l3=0.f;
      ushort4 e0 = LDE(0), e1 = LDE(1), e2 = LDE(2), e3 = LDE(3);
#define PRD(EC, KK) { \
      const float qh = eqh[u0 + (KK)], ql = eql[u0 + (KK)], w = Vw[u0 + (KK)]; \
      const float f0 = bf2f(EC.x), f1 = bf2f(EC.y), f2 = bf2f(EC.z), f3 = bf2f(EC.w); \
      h0 = fmaf(w, __builtin_amdgcn_rcpf(fmaf(qh, f0, 1.f)), h0); \
      h1 = fmaf(w, __builtin_amdgcn_rcpf(fmaf(qh, f1, 1.f)), h1); \
      h2 = fmaf(w, __builtin_amdgcn_rcpf(fmaf(qh, f2, 1.f)), h2); \
      h3 = fmaf(w, __builtin_amdgcn_rcpf(fmaf(qh, f3, 1.f)), h3); \
      l0 = fmaf(w, __builtin_amdgcn_rcpf(fmaf(ql, f0, 1.f)), l0); \
      l1 = fmaf(w, __builtin_amdgcn_rcpf(fmaf(ql, f1, 1.f)), l1); \
      l2 = fmaf(w, __builtin_amdgcn_rcpf(fmaf(ql, f2, 1.f)), l2); \
      l3 = fmaf(w, __builtin_amdgcn_rcpf(fmaf(ql, f3, 1.f)), l3); }
      for (int k = 0; k < 64; k += 4) {
        // prefetch overshoot (<= Ev row 131) lands in Vt ws region: valid memory
        ushort4 n;
        n = LDE(k + 4); PRD(e0, k + 0); e0 = n;
        n = LDE(k + 5); PRD(e1, k + 1); e1 = n;
        n = LDE(k + 6); PRD(e2, k + 2); e2 = n;
        n = LDE(k + 7); PRD(e3, k + 3); e3 = n;
      }
#undef PRD
      *(float4*)&so[SEQ + jb] = make_float4(h0, h1, h2, h3);
      *(float4*)&so[jb]       = make_float4(l0, l1, l2, l3);
    } else if (jb <= jhi) {         // waves 1,3: jb >= 256 -> hi only
      float h0=0.f,h1=0.f,h2=0.f,h3=0.f;
      ushort4 e0 = LDE(0), e1 = LDE(1), e2 = LDE(2), e3 = LDE(3);
#define PRS(EC, KK) { \
      const float qh = eqh[u0 + (KK)], w = Vw[u0 + (KK)]; \
      h0 = fmaf(w, __builtin_amdgcn_rcpf(fmaf(qh, bf2f(EC.x), 1.f)), h0); \
      h1 = fmaf(w, __builtin_amdgcn_rcpf(fmaf(qh, bf2f(EC.y), 1.f)), h1); \
      h2 = fmaf(w, __builtin_amdgcn_rcpf(fmaf(qh, bf2f(EC.z), 1.f)), h2); \
      h3 = fmaf(w, __builtin_amdgcn_rcpf(fmaf(qh, bf2f(EC.w), 1.f)), h3); }
      for (int k = 0; k < 64; k += 4) {
        ushort4 n;
        n = LDE(k + 4); PRS(e0, k + 0); e0 = n;
        n = LDE(k + 5); PRS(e1, k + 1); e1 = n;
        n = LDE(k + 6); PRS(e2, k + 2); e2 = n;
        n = LDE(k + 7); PRS(e3, k + 3); e3 = n;
      }
#undef PRS
      *(float4*)&so[SEQ + jb] = make_float4(h0, h1, h2, h3);
    }
#undef LDE
  }
  __syncthreads();

  // ---- phase B (r7): softmax, wave0 -> low row, wave1 -> high row ----
  {
    const int w = t >> 6, l = t & 63;
    if (w < 2) {
      const int jmax = (w == 0) ? i : jhi;
      float* __restrict__ r0p = sc + w * SEQ;
      const float* __restrict__ r1p = scp + w * SEQ;
      float m = 1e30f;                           // min sdot == max score
      for (int j = l; j <= jmax; j += 64) m = fminf(m, r0p[j] + r1p[j]);
#pragma unroll
      for (int o = 32; o; o >>= 1) m = fminf(m, __shfl_xor(m, o));
      float sum = 0.f;
      for (int j = l; j <= jmax; j += 64) {
        const float pr = __builtin_amdgcn_exp2f((m - (r0p[j] + r1p[j])) * CSC);
        r0p[j] = pr;
        sum += pr;
      }
#pragma unroll
      for (int o = 32; o; o >>= 1) sum += __shfl_xor(sum, o);
      if (l == 0) invs[w] = __builtin_amdgcn_rcpf(sum);
    }
  }
  __syncthreads();

  // ---- epilogue: normalized f16 P with explicit zeros in every masked slot ----
  {
    const float invLo = invs[0], invHi = invs[1];
    const int t2 = t + 256;
    const float pLo = (t <= i) ? sc[t] * invLo : 0.f;          // lo cols [0,256)
    const float pHa = sc[SEQ + t] * invHi;                      // t <= 255 <= jhi
    const float pHb = (t2 <= jhi) ? sc[SEQ + t2] * invHi : 0.f; // hi cols [256,512)
    P[(size_t)(bS + i) * SEQ + t]    = (_Float16)pLo;
    P[(size_t)(bS + ihi) * SEQ + t]  = (_Float16)pHa;
    P[(size_t)(bS + ihi) * SEQ + t2] = (_Float16)pHb;
  }
}

// ---- ctx: out = P @ values via MFMA 16x16x32 f16.
// block = (b, row-tile ri, col-group cg); wave g -> 16-col tile d0 = cg*64+g*16.
// Verified layouts: A[m=lane&15][k=(lane>>4)*8+j]; B mirrored (outer=lane&15, fed
// from Vt so 16B contiguous); D col=lane&15, row=(lane>>4)*4+reg.
__global__ __launch_bounds__(256) void ctx_kernel(
    const _Float16* __restrict__ P, const _Float16* __restrict__ Vt,
    float* __restrict__ out) {
  const int t = threadIdx.x, lane = t & 63, g = t >> 6;
  const int x = blockIdx.x;
  const int b = x >> 7, ri = (x >> 2) & 31, cg = x & 3;
  const int bS = b * SEQ;
  const int d0 = cg * 64 + g * 16;
  const int m = lane & 15, q = lane >> 4;
  const int Kmax = 16 * ri + 16;                 // causal cap for this row tile

  const _Float16* __restrict__ pA = P  + (size_t)(bS + 16 * ri + m) * SEQ + q * 8;
  const _Float16* __restrict__ pB = Vt + (size_t)(d0 + m) * BSZ + bS + q * 8;
  float4v acc = {0.f, 0.f, 0.f, 0.f};
  for (int k0 = 0; k0 < Kmax; k0 += 32) {
    const half8 a  = *(const half8*)(pA + k0);
    const half8 bv = *(const half8*)(pB + k0);
    acc = __builtin_amdgcn_mfma_f32_16x16x32_f16(a, bv, acc, 0, 0, 0);
  }
  float* __restrict__ o = out + (size_t)(bS + 16 * ri + q * 4) * DIM + d0 + m;
#pragma unroll
  for (int r = 0; r < 4; ++r) o[(size_t)r * DIM] = acc[r];
}

extern "C" void kernel_launch(void* const* d_in, const int* in_sizes, int n_in,
                              void* d_out, int out_size, void* d_ws, size_t ws_size,
                              hipStream_t stream) {
  const float* values = (const float*)d_in[0];
  const float* Wq     = (const float*)d_in[1];
  const float* Wv     = (const float*)d_in[2];
  const float* Vw     = (const float*)d_in[3];
  float* out = (float*)d_out;
  float* Eq = (float*)d_ws;                                       // 1 MB
  unsigned short* Ev = (unsigned short*)(Eq + (size_t)BSZ * UN);  // 512 KB
  _Float16* Vt = (_Float16*)(Ev + (size_t)UN * BSZ);              // [DIM][BSZ] 1 MB
  _Float16* P  = Vt + (size_t)DIM * BSZ;                          // [BSZ][SEQ] 2 MB
  proj_kernel<<<dim3(BSZ / 4), 256, 0, stream>>>(values, Wq, Wv, Eq, Ev, Vt);
  score_kernel<<<dim3(4 * 256), 256, 0, stream>>>(Eq, Ev, Vw, P);
  ctx_kernel<<<dim3(4 * 32 * 4), 256, 0, stream>>>(P, Vt, out);
}